// Round 1
// baseline (90.913 us; speedup 1.0000x reference)
//
#include <hip/hip_runtime.h>

// Spherical harmonics (lmax=3, normalize=True, component normalization)
// over edge vectors. pos: [N,3] f32; edge_index: [2,E] int; out: [E,16] f32.

#define SQ3f 1.7320508075688772f
#define SQ5f 2.2360679774997896f
#define SQ7f 2.6457513110645907f
#define C30f 0.9128709291752769f   // sqrt(5/6)
#define C32f 0.6123724356957945f   // sqrt(3/8)

__global__ __launch_bounds__(256) void sh_edge_kernel(
    const float* __restrict__ pos,
    const int* __restrict__ eidx,
    float* __restrict__ out,
    int E)
{
    int e = blockIdx.x * blockDim.x + threadIdx.x;
    if (e >= E) return;

    int s = eidx[e];       // sender (row 0)
    int d = eidx[E + e];   // receiver (row 1)

    float vx = pos[3 * s + 0] - pos[3 * d + 0];
    float vy = pos[3 * s + 1] - pos[3 * d + 1];
    float vz = pos[3 * s + 2] - pos[3 * d + 2];

    float r2 = vx * vx + vy * vy + vz * vz;
    float r = sqrtf(r2);
    float inv = 1.0f / fmaxf(r, 1e-12f);   // matches reference max(r, EPS)

    float x = vx * inv;
    float y = vy * inv;
    float z = vz * inv;

    float x2 = x * x;
    float y2 = y * y;
    float z2 = z * z;
    float x2z2 = x2 + z2;

    float s20 = SQ3f * x * z;
    float s21 = SQ3f * x * y;
    float s22 = y2 - 0.5f * x2z2;
    float s23 = SQ3f * y * z;
    float s24 = 0.5f * SQ3f * (z2 - x2);

    float fy2 = 4.0f * y2 - x2z2;

    float s30 = C30f * (s20 * z + s24 * x);
    float s31 = SQ5f * s20 * y;
    float s32 = C32f * fy2 * x;
    float s33 = 0.5f * y * (2.0f * y2 - 3.0f * x2z2);
    float s34 = C32f * z * fy2;
    float s35 = SQ5f * s24 * y;
    float s36 = C30f * (s24 * z - s20 * x);

    float4* o = reinterpret_cast<float4*>(out + (size_t)e * 16);
    o[0] = make_float4(1.0f, SQ3f * x, SQ3f * y, SQ3f * z);
    o[1] = make_float4(SQ5f * s20, SQ5f * s21, SQ5f * s22, SQ5f * s23);
    o[2] = make_float4(SQ5f * s24, SQ7f * s30, SQ7f * s31, SQ7f * s32);
    o[3] = make_float4(SQ7f * s33, SQ7f * s34, SQ7f * s35, SQ7f * s36);
}

extern "C" void kernel_launch(void* const* d_in, const int* in_sizes, int n_in,
                              void* d_out, int out_size, void* d_ws, size_t ws_size,
                              hipStream_t stream)
{
    const float* pos = (const float*)d_in[0];
    const int* eidx = (const int*)d_in[1];
    float* out = (float*)d_out;

    int E = in_sizes[1] / 2;
    int block = 256;
    int grid = (E + block - 1) / block;
    sh_edge_kernel<<<grid, block, 0, stream>>>(pos, eidx, out, E);
}

// Round 2
// 49.586 us; speedup vs baseline: 1.8334x; 1.8334x over previous
//
#include <hip/hip_runtime.h>

// Spherical harmonics (lmax=3, normalize=True, component normalization)
// over edge vectors. pos: [N,3] f32; edge_index: [2,E] int; out: [E,16] f32.
//
// 4 threads per edge: each thread computes the full SH (VALU is nearly idle)
// and stores ONE float4 quarter, so wave stores are perfectly coalesced
// (consecutive lanes -> consecutive 16B). The quarter select is branchless
// (single store instruction for all lanes) to preserve coalescing.

#define SQ3f 1.7320508075688772f
#define SQ5f 2.2360679774997896f
#define SQ7f 2.6457513110645907f
#define C30f 0.9128709291752769f   // sqrt(5/6)
#define C32f 0.6123724356957945f   // sqrt(3/8)

__global__ __launch_bounds__(256) void sh_edge_kernel(
    const float* __restrict__ pos,
    const int* __restrict__ eidx,
    float4* __restrict__ out4,
    int E)
{
    long long g = (long long)blockIdx.x * blockDim.x + threadIdx.x;
    int e = (int)(g >> 2);
    int q = (int)(g & 3);
    if (e >= E) return;

    int s = eidx[e];       // sender (row 0)
    int d = eidx[E + e];   // receiver (row 1)

    float vx = pos[3 * s + 0] - pos[3 * d + 0];
    float vy = pos[3 * s + 1] - pos[3 * d + 1];
    float vz = pos[3 * s + 2] - pos[3 * d + 2];

    float r2 = vx * vx + vy * vy + vz * vz;
    float r = sqrtf(r2);
    float inv = 1.0f / fmaxf(r, 1e-12f);   // matches reference max(r, EPS)

    float x = vx * inv;
    float y = vy * inv;
    float z = vz * inv;

    float x2 = x * x;
    float y2 = y * y;
    float z2 = z * z;
    float x2z2 = x2 + z2;

    float s20 = SQ3f * x * z;
    float s21 = SQ3f * x * y;
    float s22 = y2 - 0.5f * x2z2;
    float s23 = SQ3f * y * z;
    float s24 = 0.5f * SQ3f * (z2 - x2);

    float fy2 = 4.0f * y2 - x2z2;

    float s30 = C30f * (s20 * z + s24 * x);
    float s31 = SQ5f * s20 * y;
    float s32 = C32f * fy2 * x;
    float s33 = 0.5f * y * (2.0f * y2 - 3.0f * x2z2);
    float s34 = C32f * z * fy2;
    float s35 = SQ5f * s24 * y;
    float s36 = C30f * (s24 * z - s20 * x);

    // Quarters of the 16-float output row.
    float a0 = 1.0f,        a1 = SQ3f * x,   a2 = SQ3f * y,   a3 = SQ3f * z;
    float b0 = SQ5f * s20,  b1 = SQ5f * s21, b2 = SQ5f * s22, b3 = SQ5f * s23;
    float c0 = SQ5f * s24,  c1 = SQ7f * s30, c2 = SQ7f * s31, c3 = SQ7f * s32;
    float d0 = SQ7f * s33,  d1 = SQ7f * s34, d2 = SQ7f * s35, d3 = SQ7f * s36;

    // Branchless 4-way select (v_cndmask chains) so ALL lanes execute the
    // same single store -> coalesced.
    bool lo = (q < 2);
    bool ev = ((q & 1) == 0);
    float w0 = lo ? (ev ? a0 : b0) : (ev ? c0 : d0);
    float w1 = lo ? (ev ? a1 : b1) : (ev ? c1 : d1);
    float w2 = lo ? (ev ? a2 : b2) : (ev ? c2 : d2);
    float w3 = lo ? (ev ? a3 : b3) : (ev ? c3 : d3);

    out4[g] = make_float4(w0, w1, w2, w3);
}

extern "C" void kernel_launch(void* const* d_in, const int* in_sizes, int n_in,
                              void* d_out, int out_size, void* d_ws, size_t ws_size,
                              hipStream_t stream)
{
    const float* pos = (const float*)d_in[0];
    const int* eidx = (const int*)d_in[1];
    float4* out4 = (float4*)d_out;

    int E = in_sizes[1] / 2;
    long long total = 4LL * E;
    int block = 256;
    long long grid = (total + block - 1) / block;
    sh_edge_kernel<<<(int)grid, block, 0, stream>>>(pos, eidx, out4, E);
}

// Round 3
// 44.566 us; speedup vs baseline: 2.0399x; 1.1126x over previous
//
#include <hip/hip_runtime.h>

// Spherical harmonics (lmax=3, normalize=True, component normalization)
// over edge vectors. pos: [N,3] f32; edge_index: [2,E] int; out: [E,16] f32.
//
// 1 thread per edge (no redundant gathers), LDS-transposed output:
//   compute 16 floats -> swizzled LDS rows -> block streams the 16 KB tile
//   out as perfectly coalesced float4 stores.
// LDS swizzle: float4 slot q of row t lives at column q ^ ((t>>1)&3), which
// distributes the 64 lanes of every ds_write_b128 / ds_read_b128 evenly over
// all 32 banks (8-cycle floor, zero excess conflicts) in BOTH phases.

#define SQ3f 1.7320508075688772f
#define SQ5f 2.2360679774997896f
#define SQ7f 2.6457513110645907f
#define C30f 0.9128709291752769f   // sqrt(5/6)
#define C32f 0.6123724356957945f   // sqrt(3/8)

__global__ __launch_bounds__(256) void sh_edge_kernel(
    const float* __restrict__ pos,
    const int* __restrict__ eidx,
    float4* __restrict__ out4,
    int E)
{
    __shared__ float lds[256 * 16];   // 16 KB

    const int t = threadIdx.x;
    const long long blk = blockIdx.x;
    const long long e = blk * 256 + t;

    if (e < E) {
        int s = eidx[e];       // sender (row 0)
        int d = eidx[E + e];   // receiver (row 1)

        float vx = pos[3 * s + 0] - pos[3 * d + 0];
        float vy = pos[3 * s + 1] - pos[3 * d + 1];
        float vz = pos[3 * s + 2] - pos[3 * d + 2];

        float r2 = vx * vx + vy * vy + vz * vz;
        float r = sqrtf(r2);
        float inv = 1.0f / fmaxf(r, 1e-12f);   // matches reference max(r, EPS)

        float x = vx * inv;
        float y = vy * inv;
        float z = vz * inv;

        float x2 = x * x;
        float y2 = y * y;
        float z2 = z * z;
        float x2z2 = x2 + z2;

        float s20 = SQ3f * x * z;
        float s21 = SQ3f * x * y;
        float s22 = y2 - 0.5f * x2z2;
        float s23 = SQ3f * y * z;
        float s24 = 0.5f * SQ3f * (z2 - x2);

        float fy2 = 4.0f * y2 - x2z2;

        float s30 = C30f * (s20 * z + s24 * x);
        float s31 = SQ5f * s20 * y;
        float s32 = C32f * fy2 * x;
        float s33 = 0.5f * y * (2.0f * y2 - 3.0f * x2z2);
        float s34 = C32f * z * fy2;
        float s35 = SQ5f * s24 * y;
        float s36 = C30f * (s24 * z - s20 * x);

        float4 val[4];
        val[0] = make_float4(1.0f,        SQ3f * x,   SQ3f * y,   SQ3f * z);
        val[1] = make_float4(SQ5f * s20,  SQ5f * s21, SQ5f * s22, SQ5f * s23);
        val[2] = make_float4(SQ5f * s24,  SQ7f * s30, SQ7f * s31, SQ7f * s32);
        val[3] = make_float4(SQ7f * s33,  SQ7f * s34, SQ7f * s35, SQ7f * s36);

        #pragma unroll
        for (int q = 0; q < 4; ++q) {
            int col = q ^ ((t >> 1) & 3);
            *reinterpret_cast<float4*>(&lds[t * 16 + 4 * col]) = val[q];
        }
    }

    __syncthreads();

    // Stream the block's 1024 float4s out, coalesced.
    const size_t base4 = (size_t)blk * 1024;
    const size_t total4 = (size_t)E * 4;
    #pragma unroll
    for (int j = 0; j < 4; ++j) {
        int k = j * 256 + t;             // 0..1023 within the tile
        int r = k >> 2;                  // source LDS row (edge within block)
        int qq = k & 3;                  // float4 slot within that row
        int col = qq ^ ((r >> 1) & 3);   // undo swizzle
        float4 v = *reinterpret_cast<const float4*>(&lds[r * 16 + 4 * col]);
        size_t o = base4 + k;
        if (o < total4) out4[o] = v;
    }
}

extern "C" void kernel_launch(void* const* d_in, const int* in_sizes, int n_in,
                              void* d_out, int out_size, void* d_ws, size_t ws_size,
                              hipStream_t stream)
{
    const float* pos = (const float*)d_in[0];
    const int* eidx = (const int*)d_in[1];
    float4* out4 = (float4*)d_out;

    int E = in_sizes[1] / 2;
    int block = 256;
    int grid = (int)(((long long)E + block - 1) / block);
    sh_edge_kernel<<<grid, block, 0, stream>>>(pos, eidx, out4, E);
}